// Round 9
// baseline (553.564 us; speedup 1.0000x reference)
//
#include <hip/hip_runtime.h>
#include <hip/hip_fp16.h>
#include <math.h>

#define HW_ (512*512)

typedef float vf4 __attribute__((ext_vector_type(4)));

// ---------- wave (64-lane) butterfly sum ----------
__device__ __forceinline__ float wred(float v){
#pragma unroll
  for (int o = 32; o > 0; o >>= 1) v += __shfl_xor(v, o, 64);
  return v;
}

// ---------- tap loader: 2 channels (c0, c0+1) at pixel (y,x) ----------
template<bool TR>
__device__ __forceinline__ float2 tap(const void* __restrict__ f, int y, int x, int c0){
  if (TR){
    const __half2* p = (const __half2*)f + (((size_t)((y << 9) + x)) << 6) + (c0 >> 1);
    return __half22float2(*p);
  } else {
    const float* ff = (const float*)f;
    int base = (y << 9) + x;
    float2 r;
    r.x = ff[(size_t)c0 * HW_ + base];
    r.y = ff[(size_t)(c0 + 1) * HW_ + base];
    return r;
  }
}

// ---------- f + sobel-gradient bilinear samples from a 4x4 patch ----------
__device__ __forceinline__ void fgrad(const float P[16], float w00, float w01, float w10, float w11,
                                      float& f, float& gx, float& gy){
  f = w00*P[5] + w01*P[6] + w10*P[9] + w11*P[10];
  float gx11 = (P[2]  + 2.f*P[6]  + P[10] - P[0] - 2.f*P[4]  - P[8] ) * 0.125f;
  float gx12 = (P[3]  + 2.f*P[7]  + P[11] - P[1] - 2.f*P[5]  - P[9] ) * 0.125f;
  float gx21 = (P[6]  + 2.f*P[10] + P[14] - P[4] - 2.f*P[8]  - P[12]) * 0.125f;
  float gx22 = (P[7]  + 2.f*P[11] + P[15] - P[5] - 2.f*P[9]  - P[13]) * 0.125f;
  gx = w00*gx11 + w01*gx12 + w10*gx21 + w11*gx22;
  float gy11 = (P[8]  + 2.f*P[9]  + P[10] - P[0] - 2.f*P[1]  - P[2] ) * 0.125f;
  float gy12 = (P[9]  + 2.f*P[10] + P[11] - P[1] - 2.f*P[2]  - P[3] ) * 0.125f;
  float gy21 = (P[12] + 2.f*P[13] + P[14] - P[4] - 2.f*P[5]  - P[6] ) * 0.125f;
  float gy22 = (P[13] + 2.f*P[14] + P[15] - P[5] - 2.f*P[6]  - P[7] ) * 0.125f;
  gy = w00*gy11 + w01*gy12 + w10*gy21 + w11*gy22;
}

// ---------- cost at a point with RAW fref ----------
template<bool TR>
__device__ __forceinline__ float cost_point_raw(const void* __restrict__ fmap,
                                                const float* __restrict__ fref,
                                                int n, float px, float py, int lane){
  int c0 = 2 * lane;
  float x0f = fminf(fmaxf(floorf(px), 0.f), 511.f);
  float y0f = fminf(fmaxf(floorf(py), 0.f), 511.f);
  int x0 = (int)x0f, y0 = (int)y0f;
  int x1 = min(x0 + 1, 511), y1 = min(y0 + 1, 511);
  float wx = px - x0f, wy = py - y0f;
  float w00 = (1.f-wx)*(1.f-wy), w01 = wx*(1.f-wy), w10 = (1.f-wx)*wy, w11 = wx*wy;
  float2 a = tap<TR>(fmap, y0, x0, c0), b = tap<TR>(fmap, y0, x1, c0);
  float2 c = tap<TR>(fmap, y1, x0, c0), d = tap<TR>(fmap, y1, x1, c0);
  float f0 = w00*a.x + w01*b.x + w10*c.x + w11*d.x;
  float f1 = w00*a.y + w01*b.y + w10*c.y + w11*d.y;
  const float2 fr = *(const float2*)(fref + (size_t)n*128 + c0);
  float Sff  = wred(f0*f0 + f1*f1);
  float Sffr = wred(f0*fr.x + f1*fr.y);
  float Sfr  = wred(fr.x*fr.x + fr.y*fr.y);
  float inv = 1.f / fmaxf(sqrtf(Sff), 1e-12f);
  float irn = 1.f / fmaxf(sqrtf(Sfr), 1e-12f);
  return Sff*inv*inv - 2.f*Sffr*inv*irn + Sfr*irn*irn;
}

// ---------- transpose (C,H,W) fp32 -> (H*W, C) fp16; block 0 zeroes accumulators ----------
__global__ __launch_bounds__(512) void transpose_kernel(const float* __restrict__ fq,
                                                        __half* __restrict__ ftr,
                                                        double* __restrict__ cur2){
  __shared__ __half tile[256 * 128];
  int t = threadIdx.x;
  if (blockIdx.x == 0 && t < 256) cur2[t] = 0.0;
  int sb = blockIdx.x << 8;
  int l = t & 63, r = t >> 6;
  int px0 = l << 2;
#pragma unroll
  for (int p = 0; p < 16; p++){
    int ch = p * 8 + r;
    vf4 v = __builtin_nontemporal_load((const vf4*)(fq + (size_t)ch * HW_ + sb + px0));
#pragma unroll
    for (int j = 0; j < 4; j++){
      int px = px0 + j;
      tile[px * 128 + (ch ^ (px & 0x78))] = __float2half(v[j]);
    }
  }
  __syncthreads();
#pragma unroll
  for (int p = 0; p < 8; p++){
    int px = p * 32 + (t >> 4);
    int c8 = (t & 15) << 3;
    int cs = c8 ^ (px & 0x78);
    uint4 v = *(const uint4*)&tile[px * 128 + cs];
    *(uint4*)(ftr + ((size_t)(sb + px) << 7) + c8) = v;
  }
}

// ---------- fallback accumulator init ----------
__global__ void init_kernel(double* __restrict__ cur2){
  if (threadIdx.x < 256) cur2[threadIdx.x] = 0.0;
}

// ---------- fused eval at a pose: cost + raw Grad(6) + raw Hess(21) ----------
// R6's proven shape: 512 thr, 8 waves, 1 point/wave. Tail: atomic 8-set accumulate.
// mode 0 (initial): writes costI and costF. mode 1 (trial): prologue costT->costF
// copy if last trial accepted (state[32]); writes costT.
template<bool TR>
__global__ __launch_bounds__(512) void eval_kernel(
    const float* __restrict__ p3D, const float* __restrict__ fref,
    const void* __restrict__ fmap, const float* __restrict__ Km,
    const float* __restrict__ Rm, const float* __restrict__ tm,
    const float* __restrict__ state, double* __restrict__ cur2,
    float* __restrict__ costT, float* __restrict__ costF,
    float* __restrict__ costI, int N, int mode)
{
  int t = threadIdx.x;
  int lane = t & 63;
  int wv = t >> 6;                   // 8 waves
  int n = blockIdx.x * 8 + wv;
  if (mode == 1 && state[32] != 0.f){
    int gid = blockIdx.x * 512 + t;
    if (gid < N) costF[gid] = costT[gid];
  }
  double acc = 0.0;
  if (n < N){
    float fx = Km[0], fy = Km[4], cx = Km[2], cy = Km[5];
    float R0=Rm[0],R1=Rm[1],R2=Rm[2],R3=Rm[3],R4=Rm[4];
    float R5=Rm[5],R6=Rm[6],R7=Rm[7],R8=Rm[8];
    float t0=tm[0], t1=tm[1], t2=tm[2];
    float PX = p3D[3*n], PY = p3D[3*n+1], PZ = p3D[3*n+2];
    float X = R0*PX + R1*PY + R2*PZ + t0;
    float Y = R3*PX + R4*PY + R5*PZ + t1;
    float D = R6*PX + R7*PY + R8*PZ + t2;
    float px = X / D * fx + cx;
    float py = Y / D * fy + cy;
    bool valid = (px >= 1.f && px < 511.f && py >= 1.f && py < 511.f);
    float se2 = 0.f;
    if (valid){
      int c0 = 2 * lane;
      float x0f = fminf(fmaxf(floorf(px), 0.f), 511.f);
      float y0f = fminf(fmaxf(floorf(py), 0.f), 511.f);
      int x0 = (int)x0f, y0 = (int)y0f;
      int x1 = min(x0 + 1, 511), y1 = min(y0 + 1, 511);
      float wx = px - x0f, wy = py - y0f;
      int xs[4] = {max(x0-1,0), x0, x1, min(x1+1,511)};
      int ys[4] = {max(y0-1,0), y0, y1, min(y1+1,511)};
      float Pa[16], Pb[16];
#pragma unroll
      for (int r = 0; r < 4; r++)
#pragma unroll
        for (int sc = 0; sc < 4; sc++){
          float2 v = tap<TR>(fmap, ys[r], xs[sc], c0);
          Pa[r*4+sc] = v.x; Pb[r*4+sc] = v.y;
        }
      float w00 = (1.f-wx)*(1.f-wy), w01 = wx*(1.f-wy), w10 = (1.f-wx)*wy, w11 = wx*wy;
      float f0, gx0, gy0, f1, gx1, gy1;
      fgrad(Pa, w00, w01, w10, w11, f0, gx0, gy0);
      fgrad(Pb, w00, w01, w10, w11, f1, gx1, gy1);
      const float2 fr2 = *(const float2*)(fref + (size_t)n*128 + c0);
      // ---- 10 raw sums, ONE parallel reduction phase ----
      float Sff   = wred(f0*f0   + f1*f1);
      float Sffr0 = wred(f0*fr2.x + f1*fr2.y);
      float Sfr   = wred(fr2.x*fr2.x + fr2.y*fr2.y);
      float Sfgx  = wred(f0*gx0  + f1*gx1);
      float Sfgy  = wred(f0*gy0  + f1*gy1);
      float Sgxf0 = wred(gx0*fr2.x + gx1*fr2.y);
      float Sgyf0 = wred(gy0*fr2.x + gy1*fr2.y);
      float Sgxgx = wred(gx0*gx0 + gx1*gx1);
      float Sgxgy = wred(gx0*gy0 + gx1*gy1);
      float Sgygy = wred(gy0*gy0 + gy1*gy1);
      float irn = 1.f / fmaxf(sqrtf(Sfr), 1e-12f);
      float Sffr = Sffr0*irn, Sgxfr = Sgxf0*irn, Sgyfr = Sgyf0*irn, Sfrn = Sfr*irn*irn;
      float nrm = fmaxf(sqrtf(Sff), 1e-12f);
      float inv = 1.f/nrm, inv2 = inv*inv, inv3 = inv2*inv, inv4 = inv2*inv2;
      se2 = Sff*inv2 - 2.f*Sffr*inv + Sfrn;
      float gex = Sfgx*inv2 - Sgxfr*inv - Sfgx*Sff*inv4 + Sfgx*Sffr*inv3;
      float gey = Sfgy*inv2 - Sgyfr*inv - Sfgy*Sff*inv4 + Sfgy*Sffr*inv3;
      float sxx = Sgxgx*inv2 - Sfgx*Sfgx*inv4;
      float sxy = Sgxgy*inv2 - Sfgx*Sfgy*inv4;
      float syy = Sgygy*inv2 - Sfgy*Sfgy*inv4;
      float invD = 1.f / D;
      float rx = X * invD, ry = Y * invD;
      float A[6] = {fx*invD, 0.f, -fx*rx*invD, -fx*rx*ry, fx*(1.f+rx*rx), -fx*ry};
      float B[6] = {0.f, fy*invD, -fy*ry*invD, -fy*(1.f+ry*ry), fy*rx*ry, fy*rx};
      int li = 0, lj = 0;
      {
        const int pi_[21] = {0,0,0,0,0,0,1,1,1,1,1,2,2,2,2,3,3,3,4,4,5};
        const int pj_[21] = {0,1,2,3,4,5,1,2,3,4,5,2,3,4,5,3,4,5,4,5,5};
        if (lane >= 6 && lane < 27){ li = pi_[lane-6]; lj = pj_[lane-6]; }
      }
      float val = 0.f;
      if (lane < 6)        val = A[lane]*gex + B[lane]*gey;
      else if (lane < 27)  val = A[li]*A[lj]*sxx + (A[li]*B[lj] + A[lj]*B[li])*sxy + B[li]*B[lj]*syy;
      else if (lane == 27) val = se2;
      else if (lane == 28) val = 1.f;
      acc = (double)val;
    }
    if (lane == 0){
      float cv = valid ? se2 : __int_as_float(0x7fc00000);
      if (mode == 0){ costI[n] = cv; costF[n] = cv; }
      else costT[n] = cv;
    }
  }
  __shared__ double red[8][32];
  if (lane < 32) red[wv][lane] = acc;
  __syncthreads();
  if (t < 32){
    double s = 0.0;
#pragma unroll
    for (int i = 0; i < 8; i++) s += red[i][t];
    if (s != 0.0) atomicAdd(&cur2[t*8 + (blockIdx.x & 7)], s);
  }
}

// ---------- light trial-cost eval (iter 7: only cost needed) ----------
template<bool TR>
__global__ __launch_bounds__(512) void cost_kernel(
    const float* __restrict__ p3D, const float* __restrict__ fref,
    const void* __restrict__ fmap, const float* __restrict__ Km,
    const float* __restrict__ Rm, const float* __restrict__ tm,
    const float* __restrict__ state, double* __restrict__ cur2,
    float* __restrict__ costT, float* __restrict__ costF, int N)
{
  int t = threadIdx.x;
  int lane = t & 63;
  int wv = t >> 6;
  int n = blockIdx.x * 8 + wv;
  if (state[32] != 0.f){
    int gid = blockIdx.x * 512 + t;
    if (gid < N) costF[gid] = costT[gid];
  }
  double acc = 0.0;
  bool valid = false;
  float cp = 0.f;
  if (n < N){
    float fx = Km[0], fy = Km[4], cx = Km[2], cy = Km[5];
    float PX = p3D[3*n], PY = p3D[3*n+1], PZ = p3D[3*n+2];
    float X = Rm[0]*PX + Rm[1]*PY + Rm[2]*PZ + tm[0];
    float Y = Rm[3]*PX + Rm[4]*PY + Rm[5]*PZ + tm[1];
    float D = Rm[6]*PX + Rm[7]*PY + Rm[8]*PZ + tm[2];
    float px = X / D * fx + cx, py = Y / D * fy + cy;
    valid = (px >= 1.f && px < 511.f && py >= 1.f && py < 511.f);
    if (valid) cp = cost_point_raw<TR>(fmap, fref, n, px, py, lane);
    if (lane == 0) costT[n] = valid ? cp : __int_as_float(0x7fc00000);
    if (valid){
      if (lane == 27) acc = (double)cp;
      else if (lane == 28) acc = 1.0;
    }
  }
  __shared__ double red[8][32];
  if (lane < 32) red[wv][lane] = acc;
  __syncthreads();
  if (t < 32){
    double s = 0.0;
#pragma unroll
    for (int i = 0; i < 8; i++) s += red[i][t];
    if (s != 0.0) atomicAdd(&cur2[t*8 + (blockIdx.x & 7)], s);
  }
}

// ---------- LM solve from cached raw sums; writes trial pose to state[12..23] ----------
__device__ void solve_step(const double* __restrict__ cur, float* __restrict__ state){
  const int pi_[21] = {0,0,0,0,0,0,1,1,1,1,1,2,2,2,2,3,3,3,4,4,5};
  const int pj_[21] = {0,1,2,3,4,5,1,2,3,4,5,2,3,4,5,3,4,5,4,5,5};
  double rg[6]; for (int i = 0; i < 6; i++) rg[i] = cur[i];
  double rh[6][6];
  for (int k = 0; k < 21; k++){ rh[pi_[k]][pj_[k]] = cur[6+k]; rh[pj_[k]][pi_[k]] = cur[6+k]; }
  float jac[6];
  for (int j = 0; j < 6; j++) jac[j] = state[24+j];
  double lam = (double)state[30];
  double H[6][7];
  for (int i = 0; i < 6; i++)
    for (int j = 0; j < 6; j++) H[i][j] = (double)jac[i] * (double)jac[j] * rh[i][j];
  for (int i = 0; i < 6; i++) H[i][i] += (H[i][i] + 1e-9) * lam;
  for (int i = 0; i < 6; i++) H[i][6] = -((double)jac[i] * rg[i]);
  for (int k = 0; k < 6; k++){
    int p = k; double mx = fabs(H[k][k]);
    for (int r = k+1; r < 6; r++) if (fabs(H[r][k]) > mx){ mx = fabs(H[r][k]); p = r; }
    if (p != k) for (int c = k; c < 7; c++){ double tmp = H[k][c]; H[k][c] = H[p][c]; H[p][c] = tmp; }
    double inv = 1.0 / H[k][k];
    for (int r = k+1; r < 6; r++){
      double m = H[r][k] * inv;
      for (int c = k; c < 7; c++) H[r][c] -= m * H[k][c];
    }
  }
  double d[6];
  for (int i = 5; i >= 0; i--){
    double sx = H[i][6];
    for (int c = i+1; c < 6; c++) sx -= H[i][c] * d[c];
    d[i] = sx / H[i][i];
  }
  for (int j = 0; j < 6; j++) d[j] *= (double)jac[j];
  double wx = d[3], wy = d[4], wz = d[5];
  double th2 = wx*wx + wy*wy + wz*wz, th = sqrt(th2);
  double Aa, Bb;
  if (th < 1e-7){ Aa = 1.0; Bb = 0.5; } else { Aa = sin(th)/th; Bb = (1.0 - cos(th))/th2; }
  double W[3][3] = {{0,-wz,wy},{wz,0,-wx},{-wy,wx,0}};
  double W2[3][3];
  for (int i = 0; i < 3; i++) for (int j = 0; j < 3; j++){
    double q = 0; for (int k = 0; k < 3; k++) q += W[i][k]*W[k][j]; W2[i][j] = q;
  }
  double dr[3][3];
  for (int i = 0; i < 3; i++) for (int j = 0; j < 3; j++)
    dr[i][j] = (i == j ? 1.0 : 0.0) + Aa*W[i][j] + Bb*W2[i][j];
  double Rc[3][3], tc[3];
  for (int i = 0; i < 3; i++){ tc[i] = state[9+i]; for (int j = 0; j < 3; j++) Rc[i][j] = state[i*3+j]; }
  for (int i = 0; i < 3; i++){
    for (int j = 0; j < 3; j++){
      double q = 0; for (int k = 0; k < 3; k++) q += dr[i][k]*Rc[k][j];
      state[12 + i*3 + j] = (float)q;
    }
    double q = 0; for (int k = 0; k < 3; k++) q += dr[i][k]*tc[k];
    state[21 + i] = (float)(q + d[i]);
  }
}

// ---------- consume accumulators; accept/reject; next solve ----------
__global__ void update_kernel(double* __restrict__ cur2, float* __restrict__ state,
                              double* __restrict__ cur,
                              const float* __restrict__ Rin, const float* __restrict__ tin,
                              int iter)
{
  __shared__ double tot[32];
  int t = threadIdx.x;
  if (t < 32){
    double s = 0.0;
#pragma unroll
    for (int k = 0; k < 8; k++){ s += cur2[t*8 + k]; cur2[t*8 + k] = 0.0; }
    tot[t] = s;
  }
  __syncthreads();
  if (t != 0) return;
  if (iter < 0){
    for (int i = 0; i < 9; i++) state[i] = Rin[i];
    for (int i = 0; i < 3; i++) state[9+i] = tin[i];
    state[30] = 0.01f;
    state[32] = 0.f;
    const int diag_k[6] = {0, 6, 11, 15, 18, 20};
    for (int j = 0; j < 6; j++)
      state[24+j] = 1.0f / (1.0f + (float)sqrt(tot[6 + diag_k[j]]));
    state[31] = (float)(tot[27] / tot[28]);
    for (int k = 0; k < 32; k++) cur[k] = tot[k];
    solve_step(cur, state);
  } else {
    float cn = (float)(tot[27] / tot[28]);
    bool acpt = (cn <= state[31]);
    float lam = state[30] * (acpt ? 0.1f : 10.f);
    state[30] = fminf(fmaxf(lam, 1e-8f), 1e4f);
    state[32] = acpt ? 1.f : 0.f;
    if (acpt){
      for (int i = 0; i < 12; i++) state[i] = state[12+i];
      state[31] = cn;
      for (int k = 0; k < 32; k++) cur[k] = tot[k];
    }
    if (iter < 7) solve_step(cur, state);
  }
}

// ---------- final: R,t + flag-select of cost_final ----------
__global__ __launch_bounds__(256) void final_kernel(const float* __restrict__ state,
                                                    const float* __restrict__ costT,
                                                    float* __restrict__ out, int N)
{
  int g = blockIdx.x * blockDim.x + threadIdx.x;
  if (g < 12) out[g] = state[g];
  if (state[32] != 0.f){
    int stride = gridDim.x * blockDim.x;
    for (int n = g; n < N; n += stride) out[12 + N + n] = costT[n];
  }
}

extern "C" void kernel_launch(void* const* d_in, const int* in_sizes, int n_in,
                              void* d_out, int out_size, void* d_ws, size_t ws_size,
                              hipStream_t stream)
{
  const float* p3D  = (const float*)d_in[0];
  const float* fref = (const float*)d_in[1];
  const float* fq   = (const float*)d_in[2];
  const float* Km   = (const float*)d_in[3];
  const float* Rin  = (const float*)d_in[4];
  const float* tin  = (const float*)d_in[5];
  float* out = (float*)d_out;
  int N = in_sizes[0] / 3;
  int NBLK = (N + 7) / 8;    // eval/cost blocks: 512 thr, 8 waves, 1 pt/wave

  char* w = (char*)d_ws;
  float*  state = (float*)w;                 // 64 floats; [32]=accept flag
  double* cur   = (double*)(w + 256);        // 32 doubles (accepted sums)
  double* cur2  = (double*)(w + 512);        // 32 slots x 8 sets (2 KB)
  float*  costT = (float*)(w + 2560);        // N floats (trial per-point cost)
  size_t ftr_off = (2560 + (size_t)N*4 + 255) & ~(size_t)255;
  __half* ftr = (__half*)(w + ftr_off);
  size_t need = ftr_off + (size_t)HW_ * 128 * 2;
  bool tr = (ws_size >= need);

  float* costI = out + 12;          // cost_init
  float* costF = out + 12 + N;      // cost_final (best-pose per-point cost)

  if (tr) transpose_kernel<<<HW_/256, 512, 0, stream>>>(fq, ftr, cur2);
  else    init_kernel<<<1, 256, 0, stream>>>(cur2);
  const void* fmap = tr ? (const void*)ftr : (const void*)fq;

  // initial eval at (Rin, tin): writes costI + costF, fills accumulators
  if (tr) eval_kernel<true ><<<NBLK, 512, 0, stream>>>(p3D, fref, fmap, Km, Rin, tin, state, cur2, costT, costF, costI, N, 0);
  else    eval_kernel<false><<<NBLK, 512, 0, stream>>>(p3D, fref, fmap, Km, Rin, tin, state, cur2, costT, costF, costI, N, 0);
  update_kernel<<<1, 64, 0, stream>>>(cur2, state, cur, Rin, tin, -1);

  for (int it = 0; it < 7; it++){
    if (tr) eval_kernel<true ><<<NBLK, 512, 0, stream>>>(p3D, fref, fmap, Km, state + 12, state + 21, state, cur2, costT, costF, nullptr, N, 1);
    else    eval_kernel<false><<<NBLK, 512, 0, stream>>>(p3D, fref, fmap, Km, state + 12, state + 21, state, cur2, costT, costF, nullptr, N, 1);
    update_kernel<<<1, 64, 0, stream>>>(cur2, state, cur, Rin, tin, it);
  }
  // iter 7: only the trial cost matters
  if (tr) cost_kernel<true ><<<NBLK, 512, 0, stream>>>(p3D, fref, fmap, Km, state + 12, state + 21, state, cur2, costT, costF, N);
  else    cost_kernel<false><<<NBLK, 512, 0, stream>>>(p3D, fref, fmap, Km, state + 12, state + 21, state, cur2, costT, costF, N);
  update_kernel<<<1, 64, 0, stream>>>(cur2, state, cur, Rin, tin, 7);

  final_kernel<<<256, 256, 0, stream>>>(state, costT, out, N);
}

// Round 10
// 471.586 us; speedup vs baseline: 1.1738x; 1.1738x over previous
//
#include <hip/hip_runtime.h>
#include <hip/hip_fp16.h>
#include <math.h>

#define HW_ (512*512)

typedef float vf4 __attribute__((ext_vector_type(4)));

// ---------- wave (64-lane) butterfly sum ----------
__device__ __forceinline__ float wred(float v){
#pragma unroll
  for (int o = 32; o > 0; o >>= 1) v += __shfl_xor(v, o, 64);
  return v;
}

// ---------- tap loader: 2 channels (c0, c0+1) at pixel (y,x) ----------
template<bool TR>
__device__ __forceinline__ float2 tap(const void* __restrict__ f, int y, int x, int c0){
  if (TR){
    const __half2* p = (const __half2*)f + (((size_t)((y << 9) + x)) << 6) + (c0 >> 1);
    return __half22float2(*p);
  } else {
    const float* ff = (const float*)f;
    int base = (y << 9) + x;
    float2 r;
    r.x = ff[(size_t)c0 * HW_ + base];
    r.y = ff[(size_t)(c0 + 1) * HW_ + base];
    return r;
  }
}

// ---------- f + sobel-gradient bilinear samples from a 4x4 patch ----------
__device__ __forceinline__ void fgrad(const float P[16], float w00, float w01, float w10, float w11,
                                      float& f, float& gx, float& gy){
  f = w00*P[5] + w01*P[6] + w10*P[9] + w11*P[10];
  float gx11 = (P[2]  + 2.f*P[6]  + P[10] - P[0] - 2.f*P[4]  - P[8] ) * 0.125f;
  float gx12 = (P[3]  + 2.f*P[7]  + P[11] - P[1] - 2.f*P[5]  - P[9] ) * 0.125f;
  float gx21 = (P[6]  + 2.f*P[10] + P[14] - P[4] - 2.f*P[8]  - P[12]) * 0.125f;
  float gx22 = (P[7]  + 2.f*P[11] + P[15] - P[5] - 2.f*P[9]  - P[13]) * 0.125f;
  gx = w00*gx11 + w01*gx12 + w10*gx21 + w11*gx22;
  float gy11 = (P[8]  + 2.f*P[9]  + P[10] - P[0] - 2.f*P[1]  - P[2] ) * 0.125f;
  float gy12 = (P[9]  + 2.f*P[10] + P[11] - P[1] - 2.f*P[2]  - P[3] ) * 0.125f;
  float gy21 = (P[12] + 2.f*P[13] + P[14] - P[4] - 2.f*P[5]  - P[6] ) * 0.125f;
  float gy22 = (P[13] + 2.f*P[14] + P[15] - P[5] - 2.f*P[6]  - P[7] ) * 0.125f;
  gy = w00*gy11 + w01*gy12 + w10*gy21 + w11*gy22;
}

// ---------- normalized-feature cost: one parallel 3-wred phase ----------
template<bool TR>
__device__ __forceinline__ float cost_point(const void* __restrict__ fmap,
                                            const float* __restrict__ frn,
                                            int n, float px, float py, int lane){
  int c0 = 2 * lane;
  float x0f = fminf(fmaxf(floorf(px), 0.f), 511.f);
  float y0f = fminf(fmaxf(floorf(py), 0.f), 511.f);
  int x0 = (int)x0f, y0 = (int)y0f;
  int x1 = min(x0 + 1, 511), y1 = min(y0 + 1, 511);
  float wx = px - x0f, wy = py - y0f;
  float w00 = (1.f-wx)*(1.f-wy), w01 = wx*(1.f-wy), w10 = (1.f-wx)*wy, w11 = wx*wy;
  float2 a = tap<TR>(fmap, y0, x0, c0), b = tap<TR>(fmap, y0, x1, c0);
  float2 c = tap<TR>(fmap, y1, x0, c0), d = tap<TR>(fmap, y1, x1, c0);
  float f0 = w00*a.x + w01*b.x + w10*c.x + w11*d.x;
  float f1 = w00*a.y + w01*b.y + w10*c.y + w11*d.y;
  const float2 fr = *(const float2*)(frn + (size_t)n*128 + c0);
  float Sff  = wred(f0*f0 + f1*f1);
  float Sffr = wred(f0*fr.x + f1*fr.y);
  float Sfr  = wred(fr.x*fr.x + fr.y*fr.y);
  float nrm = fmaxf(sqrtf(Sff), 1e-12f);
  float inv = 1.f / nrm;
  return Sff*inv*inv - 2.f*Sffr*inv + Sfr;
}

// ---------- transpose (C,H,W) fp32 -> (H*W, C) fp16 ----------
__global__ __launch_bounds__(256) void transpose_kernel(const float* __restrict__ fq,
                                                        __half* __restrict__ ftr){
  __shared__ float tf[256 * 32];
  int g  = blockIdx.x & 3;
  int sb = (blockIdx.x >> 2) << 8;
  int t = threadIdx.x;
  int l = t & 63, w = t >> 6;
  int s = l >> 4;
  int ipg = (l & 15) + (w << 4);
  int px0 = ipg << 2;
#pragma unroll
  for (int p = 0; p < 8; p++){
    int ch = s * 8 + p;
    const vf4* src = (const vf4*)(fq + (size_t)(g*32 + ch) * HW_ + sb + px0);
    vf4 v = __builtin_nontemporal_load(src);
#pragma unroll
    for (int j = 0; j < 4; j++){
      int px = px0 + j;
      int fz = ((3 * (px >> 2)) + ((px & 3) << 3)) & 31;
      tf[px * 32 + (ch ^ fz)] = v[j];
    }
  }
  __syncthreads();
#pragma unroll
  for (int q = 0; q < 4; q++){
    int px = (q << 6) + (t >> 2);
    int c8 = (t & 3) << 3;
    int fz = ((3 * (px >> 2)) + ((px & 3) << 3)) & 31;
    float v[8];
#pragma unroll
    for (int j = 0; j < 8; j++) v[j] = tf[px * 32 + ((c8 + j) ^ fz)];
    __half2 hh[4];
    hh[0] = __floats2half2_rn(v[0], v[1]);
    hh[1] = __floats2half2_rn(v[2], v[3]);
    hh[2] = __floats2half2_rn(v[4], v[5]);
    hh[3] = __floats2half2_rn(v[6], v[7]);
    *(uint4*)(ftr + ((size_t)(sb + px)) * 128 + g * 32 + c8) = *(uint4*)hh;
  }
}

// ---------- prep: normalize fref + init state ----------
// state: [0..8] R, [9..11] t, [12..20] R_new, [21..23] t_new, [24..29] jacobi,
//        [30] lam, [31] cost_best
__global__ __launch_bounds__(256) void prep_kernel(const float* __restrict__ fref,
                                                   float* __restrict__ frn,
                                                   const float* __restrict__ Rin,
                                                   const float* __restrict__ tin,
                                                   float* __restrict__ state, int N){
  if (blockIdx.x == 0){
    int t = threadIdx.x;
    if (t < 9) state[t] = Rin[t];
    if (t < 3) state[9 + t] = tin[t];
    if (t == 0) state[30] = 0.01f;
  }
  int lane = threadIdx.x & 63;
  int n = blockIdx.x * 4 + (threadIdx.x >> 6);
  if (n >= N) return;
  int c0 = 2 * lane;
  float2 fr = *(const float2*)(fref + (size_t)n*128 + c0);
  float rn = fmaxf(sqrtf(wred(fr.x*fr.x + fr.y*fr.y)), 1e-12f);
  float2 o; o.x = fr.x / rn; o.y = fr.y / rn;
  *(float2*)(frn + (size_t)n*128 + c0) = o;
}

// ---------- fused eval at pose state[po..po+11] ----------
template<bool TR>
__global__ __launch_bounds__(512) void eval_kernel(
    const float* __restrict__ p3D, const float* __restrict__ frn,
    const void* __restrict__ fmap, const float* __restrict__ Km,
    const float* __restrict__ state, int po, double* __restrict__ part,
    float* __restrict__ cost_out, int N)
{
  int t = threadIdx.x;
  int lane = t & 63;
  int wv = t >> 6;                   // 8 waves
  int n = blockIdx.x * 8 + wv;
  double acc = 0.0;
  if (n < N){
    float fx = Km[0], fy = Km[4], cx = Km[2], cy = Km[5];
    float R0=state[po+0],R1=state[po+1],R2=state[po+2],R3=state[po+3],R4=state[po+4];
    float R5=state[po+5],R6=state[po+6],R7=state[po+7],R8=state[po+8];
    float t0=state[po+9], t1=state[po+10], t2=state[po+11];
    float PX = p3D[3*n], PY = p3D[3*n+1], PZ = p3D[3*n+2];
    float X = R0*PX + R1*PY + R2*PZ + t0;
    float Y = R3*PX + R4*PY + R5*PZ + t1;
    float D = R6*PX + R7*PY + R8*PZ + t2;
    float px = X / D * fx + cx;
    float py = Y / D * fy + cy;
    bool valid = (px >= 1.f && px < 511.f && py >= 1.f && py < 511.f);
    if (valid){
      int c0 = 2 * lane;
      float x0f = fminf(fmaxf(floorf(px), 0.f), 511.f);
      float y0f = fminf(fmaxf(floorf(py), 0.f), 511.f);
      int x0 = (int)x0f, y0 = (int)y0f;
      int x1 = min(x0 + 1, 511), y1 = min(y0 + 1, 511);
      float wx = px - x0f, wy = py - y0f;
      int xs[4] = {max(x0-1,0), x0, x1, min(x1+1,511)};
      int ys[4] = {max(y0-1,0), y0, y1, min(y1+1,511)};
      float Pa[16], Pb[16];
#pragma unroll
      for (int r = 0; r < 4; r++)
#pragma unroll
        for (int scol = 0; scol < 4; scol++){
          float2 v = tap<TR>(fmap, ys[r], xs[scol], c0);
          Pa[r*4+scol] = v.x; Pb[r*4+scol] = v.y;
        }
      float w00 = (1.f-wx)*(1.f-wy), w01 = wx*(1.f-wy), w10 = (1.f-wx)*wy, w11 = wx*wy;
      float f0, gx0, gy0, f1, gx1, gy1;
      fgrad(Pa, w00, w01, w10, w11, f0, gx0, gy0);
      fgrad(Pb, w00, w01, w10, w11, f1, gx1, gy1);
      const float2 fr2 = *(const float2*)(frn + (size_t)n*128 + c0);
      // ---- 10 raw sums, ONE parallel reduction phase ----
      float Sff   = wred(f0*f0   + f1*f1);
      float Sffr  = wred(f0*fr2.x + f1*fr2.y);
      float Sfr   = wred(fr2.x*fr2.x + fr2.y*fr2.y);
      float Sfgx  = wred(f0*gx0  + f1*gx1);
      float Sfgy  = wred(f0*gy0  + f1*gy1);
      float Sgxfr = wred(gx0*fr2.x + gx1*fr2.y);
      float Sgyfr = wred(gy0*fr2.x + gy1*fr2.y);
      float Sgxgx = wred(gx0*gx0 + gx1*gx1);
      float Sgxgy = wred(gx0*gy0 + gx1*gy1);
      float Sgygy = wred(gy0*gy0 + gy1*gy1);
      float nrm = fmaxf(sqrtf(Sff), 1e-12f);
      float inv = 1.f/nrm, inv2 = inv*inv, inv3 = inv2*inv, inv4 = inv2*inv2;
      float se2 = Sff*inv2 - 2.f*Sffr*inv + Sfr;
      float gex = Sfgx*inv2 - Sgxfr*inv - Sfgx*Sff*inv4 + Sfgx*Sffr*inv3;
      float gey = Sfgy*inv2 - Sgyfr*inv - Sfgy*Sff*inv4 + Sfgy*Sffr*inv3;
      float sxx = Sgxgx*inv2 - Sfgx*Sfgx*inv4;
      float sxy = Sgxgy*inv2 - Sfgx*Sfgy*inv4;
      float syy = Sgygy*inv2 - Sfgy*Sfgy*inv4;
      float invD = 1.f / D;
      float rx = X * invD, ry = Y * invD;
      float A[6] = {fx*invD, 0.f, -fx*rx*invD, -fx*rx*ry, fx*(1.f+rx*rx), -fx*ry};
      float B[6] = {0.f, fy*invD, -fy*ry*invD, -fy*(1.f+ry*ry), fy*rx*ry, fy*rx};
      int li = 0, lj = 0;
      {
        const int pi_[21] = {0,0,0,0,0,0,1,1,1,1,1,2,2,2,2,3,3,3,4,4,5};
        const int pj_[21] = {0,1,2,3,4,5,1,2,3,4,5,2,3,4,5,3,4,5,4,5,5};
        if (lane >= 6 && lane < 27){ li = pi_[lane-6]; lj = pj_[lane-6]; }
      }
      float val = 0.f;
      if (lane < 6)        val = A[lane]*gex + B[lane]*gey;
      else if (lane < 27)  val = A[li]*A[lj]*sxx + (A[li]*B[lj] + A[lj]*B[li])*sxy + B[li]*B[lj]*syy;
      else if (lane == 27) val = se2;
      else if (lane == 28) val = 1.f;
      acc = (double)val;
      if (cost_out && lane == 0) cost_out[n] = se2;
    } else if (cost_out && lane == 0){
      cost_out[n] = __int_as_float(0x7fc00000);
    }
  }
  __shared__ double red[8][32];
  if (lane < 32) red[wv][lane] = acc;
  __syncthreads();
  if (t < 32){
    double s = 0.0;
#pragma unroll
    for (int i = 0; i < 8; i++) s += red[i][t];
    part[(size_t)blockIdx.x * 32 + t] = s;
  }
}

// ---------- light trial-cost eval for iter 7 (only cost/count slots needed) ----------
template<bool TR>
__global__ __launch_bounds__(512) void cost7_kernel(
    const float* __restrict__ p3D, const float* __restrict__ frn,
    const void* __restrict__ fmap, const float* __restrict__ Km,
    const float* __restrict__ state, int po, double* __restrict__ part, int N)
{
  int t = threadIdx.x;
  int lane = t & 63;
  int wv = t >> 6;
  int n = blockIdx.x * 8 + wv;
  double acc = 0.0;
  if (n < N){
    float fx = Km[0], fy = Km[4], cx = Km[2], cy = Km[5];
    float PX = p3D[3*n], PY = p3D[3*n+1], PZ = p3D[3*n+2];
    float X = state[po+0]*PX + state[po+1]*PY + state[po+2]*PZ + state[po+9];
    float Y = state[po+3]*PX + state[po+4]*PY + state[po+5]*PZ + state[po+10];
    float D = state[po+6]*PX + state[po+7]*PY + state[po+8]*PZ + state[po+11];
    float px = X / D * fx + cx, py = Y / D * fy + cy;
    if (px >= 1.f && px < 511.f && py >= 1.f && py < 511.f){
      float cp = cost_point<TR>(fmap, frn, n, px, py, lane);
      if (lane == 27) acc = (double)cp;
      else if (lane == 28) acc = 1.0;
    }
  }
  __shared__ double red[8][32];
  if (lane < 32) red[wv][lane] = acc;
  __syncthreads();
  if (t < 32){
    double s = 0.0;
#pragma unroll
    for (int i = 0; i < 8; i++) s += red[i][t];
    part[(size_t)blockIdx.x * 32 + t] = s;
  }
}

// ---------- LM solve from cached raw sums; writes trial pose to state[12..23] ----------
__device__ void solve_step(const double* __restrict__ cur, float* __restrict__ state){
  const int pi_[21] = {0,0,0,0,0,0,1,1,1,1,1,2,2,2,2,3,3,3,4,4,5};
  const int pj_[21] = {0,1,2,3,4,5,1,2,3,4,5,2,3,4,5,3,4,5,4,5,5};
  double rg[6]; for (int i = 0; i < 6; i++) rg[i] = cur[i];
  double rh[6][6];
  for (int k = 0; k < 21; k++){ rh[pi_[k]][pj_[k]] = cur[6+k]; rh[pj_[k]][pi_[k]] = cur[6+k]; }
  float jac[6];
  for (int j = 0; j < 6; j++) jac[j] = state[24+j];
  double lam = (double)state[30];
  double H[6][7];
  for (int i = 0; i < 6; i++)
    for (int j = 0; j < 6; j++) H[i][j] = (double)jac[i] * (double)jac[j] * rh[i][j];
  for (int i = 0; i < 6; i++) H[i][i] += (H[i][i] + 1e-9) * lam;
  for (int i = 0; i < 6; i++) H[i][6] = -((double)jac[i] * rg[i]);
  for (int k = 0; k < 6; k++){
    int p = k; double mx = fabs(H[k][k]);
    for (int r = k+1; r < 6; r++) if (fabs(H[r][k]) > mx){ mx = fabs(H[r][k]); p = r; }
    if (p != k) for (int c = k; c < 7; c++){ double tmp = H[k][c]; H[k][c] = H[p][c]; H[p][c] = tmp; }
    double inv = 1.0 / H[k][k];
    for (int r = k+1; r < 6; r++){
      double m = H[r][k] * inv;
      for (int c = k; c < 7; c++) H[r][c] -= m * H[k][c];
    }
  }
  double d[6];
  for (int i = 5; i >= 0; i--){
    double sx = H[i][6];
    for (int c = i+1; c < 6; c++) sx -= H[i][c] * d[c];
    d[i] = sx / H[i][i];
  }
  for (int j = 0; j < 6; j++) d[j] *= (double)jac[j];
  double wx = d[3], wy = d[4], wz = d[5];
  double th2 = wx*wx + wy*wy + wz*wz, th = sqrt(th2);
  double Aa, Bb;
  if (th < 1e-7){ Aa = 1.0; Bb = 0.5; } else { Aa = sin(th)/th; Bb = (1.0 - cos(th))/th2; }
  double W[3][3] = {{0,-wz,wy},{wz,0,-wx},{-wy,wx,0}};
  double W2[3][3];
  for (int i = 0; i < 3; i++) for (int j = 0; j < 3; j++){
    double q = 0; for (int k = 0; k < 3; k++) q += W[i][k]*W[k][j]; W2[i][j] = q;
  }
  double dr[3][3];
  for (int i = 0; i < 3; i++) for (int j = 0; j < 3; j++)
    dr[i][j] = (i == j ? 1.0 : 0.0) + Aa*W[i][j] + Bb*W2[i][j];
  double Rc[3][3], tc[3];
  for (int i = 0; i < 3; i++){ tc[i] = state[9+i]; for (int j = 0; j < 3; j++) Rc[i][j] = state[i*3+j]; }
  for (int i = 0; i < 3; i++){
    for (int j = 0; j < 3; j++){
      double q = 0; for (int k = 0; k < 3; k++) q += dr[i][k]*Rc[k][j];
      state[12 + i*3 + j] = (float)q;
    }
    double q = 0; for (int k = 0; k < 3; k++) q += dr[i][k]*tc[k];
    state[21 + i] = (float)(q + d[i]);
  }
}

// ---------- reduce partials; accept/reject; next solve ----------
__global__ __launch_bounds__(1024) void update_kernel(
    const double* __restrict__ part, int rows, float* __restrict__ state,
    double* __restrict__ cur, int iter)
{
  __shared__ double sm[32*32];
  __shared__ double tot[32];
  int t = threadIdx.x;
  int l = t & 31, ch = t >> 5;
  double s = 0.0;
  for (int r = ch; r < rows; r += 32) s += part[(size_t)r*32 + l];
  sm[ch*32 + l] = s;
  __syncthreads();
  if (t < 32){
    double x = 0.0;
    for (int c = 0; c < 32; c++) x += sm[c*32 + t];
    tot[t] = x;
  }
  __syncthreads();
  if (t != 0) return;

  if (iter < 0){
    const int diag_k[6] = {0, 6, 11, 15, 18, 20};
    for (int j = 0; j < 6; j++)
      state[24+j] = 1.0f / (1.0f + (float)sqrt(tot[6 + diag_k[j]]));
    state[31] = (float)(tot[27] / tot[28]);
    for (int k = 0; k < 32; k++) cur[k] = tot[k];
    solve_step(cur, state);
  } else {
    float cn = (float)(tot[27] / tot[28]);
    bool acpt = (cn <= state[31]);
    float lam = state[30] * (acpt ? 0.1f : 10.f);
    state[30] = fminf(fmaxf(lam, 1e-8f), 1e4f);
    if (acpt){
      for (int i = 0; i < 12; i++) state[i] = state[12+i];
      state[31] = cn;
      for (int k = 0; k < 32; k++) cur[k] = tot[k];
    }
    if (iter < 7) solve_step(cur, state);
  }
}

// ---------- final outputs: R, t, cost_final ----------
template<bool TR>
__global__ __launch_bounds__(256) void final_kernel(
    const float* __restrict__ p3D, const float* __restrict__ frn,
    const void* __restrict__ fmap, const float* __restrict__ Km,
    const float* __restrict__ state, float* __restrict__ out, int N)
{
  if (blockIdx.x == 0 && threadIdx.x < 12) out[threadIdx.x] = state[threadIdx.x];
  int lane = threadIdx.x & 63;
  int n = blockIdx.x * 4 + (threadIdx.x >> 6);
  if (n >= N) return;
  float fx = Km[0], fy = Km[4], cx = Km[2], cy = Km[5];
  float PX = p3D[3*n], PY = p3D[3*n+1], PZ = p3D[3*n+2];
  float X = state[0]*PX + state[1]*PY + state[2]*PZ + state[9];
  float Y = state[3]*PX + state[4]*PY + state[5]*PZ + state[10];
  float D = state[6]*PX + state[7]*PY + state[8]*PZ + state[11];
  float px = X / D * fx + cx, py = Y / D * fy + cy;
  bool vf = (px >= 1.f && px < 511.f && py >= 1.f && py < 511.f);
  float cf = __int_as_float(0x7fc00000);
  if (vf) cf = cost_point<TR>(fmap, frn, n, px, py, lane);
  if (lane == 0) out[12 + N + n] = cf;
}

extern "C" void kernel_launch(void* const* d_in, const int* in_sizes, int n_in,
                              void* d_out, int out_size, void* d_ws, size_t ws_size,
                              hipStream_t stream)
{
  const float* p3D  = (const float*)d_in[0];
  const float* fref = (const float*)d_in[1];
  const float* fq   = (const float*)d_in[2];
  const float* Km   = (const float*)d_in[3];
  const float* Rin  = (const float*)d_in[4];
  const float* tin  = (const float*)d_in[5];
  float* out = (float*)d_out;
  int N = in_sizes[0] / 3;
  int NBLK  = (N + 7) / 8;    // eval blocks (512 thr, 8 waves, 1 pt/wave)
  int NBLK4 = (N + 3) / 4;    // prep/final blocks (256 thr)

  char* w = (char*)d_ws;
  float*  state = (float*)w;            // 256 B
  double* cur   = (double*)(w + 256);   // 256 B
  double* part  = (double*)(w + 512);
  size_t part_bytes = (size_t)NBLK * 32 * 8;
  float* frn = (float*)(w + 512 + part_bytes);
  size_t frn_bytes = (size_t)N * 128 * 4;
  size_t ftr_off = (512 + part_bytes + frn_bytes + 255) & ~(size_t)255;
  __half* ftr = (__half*)(w + ftr_off);
  size_t need = ftr_off + (size_t)HW_ * 128 * 2;
  bool tr = (ws_size >= need);

  if (tr) transpose_kernel<<<(HW_/256)*4, 256, 0, stream>>>(fq, ftr);
  const void* fmap = tr ? (const void*)ftr : (const void*)fq;
  prep_kernel<<<NBLK4, 256, 0, stream>>>(fref, frn, Rin, tin, state, N);

  // initial eval also emits per-point cost_init (se2 at iter 0)
  if (tr) eval_kernel<true ><<<NBLK, 512, 0, stream>>>(p3D, frn, fmap, Km, state, 0, part, out + 12, N);
  else    eval_kernel<false><<<NBLK, 512, 0, stream>>>(p3D, frn, fmap, Km, state, 0, part, out + 12, N);
  update_kernel<<<1, 1024, 0, stream>>>(part, NBLK, state, cur, -1);

  for (int it = 0; it < 7; it++){
    if (tr) eval_kernel<true ><<<NBLK, 512, 0, stream>>>(p3D, frn, fmap, Km, state, 12, part, nullptr, N);
    else    eval_kernel<false><<<NBLK, 512, 0, stream>>>(p3D, frn, fmap, Km, state, 12, part, nullptr, N);
    update_kernel<<<1, 1024, 0, stream>>>(part, NBLK, state, cur, it);
  }
  // iter 7: only the trial cost matters (its grad/Hess would feed a nonexistent iter 8)
  if (tr) cost7_kernel<true ><<<NBLK, 512, 0, stream>>>(p3D, frn, fmap, Km, state, 12, part, N);
  else    cost7_kernel<false><<<NBLK, 512, 0, stream>>>(p3D, frn, fmap, Km, state, 12, part, N);
  update_kernel<<<1, 1024, 0, stream>>>(part, NBLK, state, cur, 7);

  if (tr) final_kernel<true ><<<NBLK4, 256, 0, stream>>>(p3D, frn, fmap, Km, state, out, N);
  else    final_kernel<false><<<NBLK4, 256, 0, stream>>>(p3D, frn, fmap, Km, state, out, N);
}